// Round 1
// baseline (823.088 us; speedup 1.0000x reference)
//
#include <hip/hip_runtime.h>
#include <hip/hip_bf16.h>
#include <cstdint>
#include <cstddef>

// LatentNeuralSDE: 100 sequential Euler-Maruyama steps, B=32768, LAT=10.
// One persistent kernel. Each block owns 64 batch rows for all 100 steps.
// Each wave owns a private 16-row slab -> NO barriers inside the step loop.
//
// Key folds:
//  - c1[m][128] = db1 + a@dW1[10:74] + r@dW1[74:106] computed once per block
//    (encoders fused in), held in 32 VGPRs/lane in MFMA C/D layout.
//  - t enters drift/diffusion as an extra K-feature (k=10) with B-row =
//    dW1[106,:] / gW1[10,:]; z-LDS row stores [z0..z9, t, 0...] as bf16.
//  - MFMA 16x16x32 bf16, fp32 accumulation; master z stays fp32 in VGPRs.

#define B_TOT 32768
#define NSTEP 100
#define HID   128
#define MT    64    // batch rows per block

typedef __attribute__((ext_vector_type(8))) short sh8;
typedef __attribute__((ext_vector_type(4))) float f32x4;

struct __align__(16) LdsSteady {
  short h[MT][136];   // h1/h2 slab (bf16), A-layout rows; pad 136 -> 2-way max
  short hg[MT][40];   // diffusion hidden (bf16)
  short zb[MT][24];   // [z0..z9, t, 0(x5 read as k=11..15), pad]; 48B rows
  float tsl[104];
};
struct __align__(16) LdsInit { float ar[MT][100]; };  // [a(64), r(32)] fp32
struct __align__(16) Lds {
  short w2t[HID][136];   // W2^T bf16: row n holds W2[:,n]; pad 136
  union { LdsSteady s; LdsInit i; } u;
};

static __device__ __forceinline__ short f2bf(float v) {  // RTNE f32->bf16
  unsigned u = __builtin_bit_cast(unsigned, v);
  u += 0x7fffu + ((u >> 16) & 1u);
  return (short)(u >> 16);
}
static __device__ __forceinline__ float tanh_fast(float x) {
  // 1 - 2/(1+e^{2x}); v_exp + v_rcp; exact at +-inf saturation
  float e = exp2f(x * 2.8853900817779268f);
  float r = __builtin_amdgcn_rcpf(e + 1.0f);
  return __builtin_fmaf(-2.0f, r, 1.0f);
}
static __device__ __forceinline__ float softplus_fast(float x) {
  float e = exp2f(x * 1.4426950408889634f);
  float l = log2f(e + 1.0f) * 0.6931471805599453f;
  return (x > 20.0f) ? x : l;
}

__global__ __launch_bounds__(256, 2)
void sde_kernel(const float* __restrict__ z0, const float* __restrict__ activity,
                const float* __restrict__ rest, const float* __restrict__ ts,
                const float* __restrict__ noise,
                const float* __restrict__ aW1, const float* __restrict__ ab1,
                const float* __restrict__ aW2, const float* __restrict__ ab2,
                const float* __restrict__ rW1, const float* __restrict__ rb1,
                const float* __restrict__ rW2, const float* __restrict__ rb2,
                const float* __restrict__ dW1, const float* __restrict__ db1,
                const float* __restrict__ dW2, const float* __restrict__ db2,
                const float* __restrict__ dW3, const float* __restrict__ db3,
                const float* __restrict__ gW1, const float* __restrict__ gb1,
                const float* __restrict__ gW2, const float* __restrict__ gb2,
                float* __restrict__ out)
{
  __shared__ Lds lds;
  const int tid  = threadIdx.x;
  const int lane = tid & 63;
  const int wave = tid >> 6;
  const int n    = lane & 15;    // MFMA col / A-row selector
  const int quad = lane >> 4;    // MFMA k-group / D-row group
  const int slab = wave * 16;    // this wave's private row slab
  const int mblk = blockIdx.x * MT;

  // ---- stage W2^T as bf16 (coalesced global read, one-time) ----
  for (int idx = tid; idx < HID * HID; idx += 256) {
    int k = idx >> 7, nn = idx & 127;
    lds.w2t[nn][k] = f2bf(dW2[idx]);      // dW2 is [k][n]
  }

  // ---- encoders -> ar slab in LDS (weights are lane-uniform -> s_loads) ----
  {
    const int e = tid >> 2, p = tid & 3;
    const int eg = mblk + e;
    float act[6], rst[3];
    #pragma unroll
    for (int i = 0; i < 6; ++i) act[i] = activity[eg * 6 + i];
    #pragma unroll
    for (int i = 0; i < 3; ++i) rst[i] = rest[eg * 3 + i];
    float ha[32];
    for (int j = 0; j < 32; ++j) {
      float s = ab1[j];
      #pragma unroll
      for (int i = 0; i < 6; ++i) s = __builtin_fmaf(act[i], aW1[i * 32 + j], s);
      ha[j] = fmaxf(s, 0.0f);
    }
    float hr[16];
    for (int j = 0; j < 16; ++j) {
      float s = rb1[j];
      #pragma unroll
      for (int i = 0; i < 3; ++i) s = __builtin_fmaf(rst[i], rW1[i * 16 + j], s);
      hr[j] = fmaxf(s, 0.0f);
    }
    for (int oo = 0; oo < 24; ++oo) {
      int o = p * 24 + oo;
      float v;
      if (o < 64) {
        v = ab2[o];
        for (int j = 0; j < 32; ++j) v = __builtin_fmaf(ha[j], aW2[j * 64 + o], v);
      } else {
        int ro = o - 64;
        v = rb2[ro];
        for (int j = 0; j < 16; ++j) v = __builtin_fmaf(hr[j], rW2[j * 32 + ro], v);
      }
      lds.u.i.ar[e][o] = v;
    }
  }
  __syncthreads();

  // ---- c1 tile -> 32 VGPRs/lane, D-layout: row=quad*4+r, col=t*16+n ----
  float c1v[8][4];
  #pragma unroll
  for (int t = 0; t < 8; ++t) {
    float b = db1[t * 16 + n];
    #pragma unroll
    for (int r = 0; r < 4; ++r) c1v[t][r] = b;
  }
  for (int k = 0; k < 96; ++k) {
    float w[8];
    #pragma unroll
    for (int t = 0; t < 8; ++t) w[t] = dW1[(10 + k) * HID + t * 16 + n];
    #pragma unroll
    for (int r = 0; r < 4; ++r) {
      float av = lds.u.i.ar[slab + quad * 4 + r][k];
      #pragma unroll
      for (int t = 0; t < 8; ++t) c1v[t][r] = __builtin_fmaf(av, w[t], c1v[t][r]);
    }
  }

  // ---- small-matrix B-fragments into registers (fixed across steps) ----
  // B-frag layout: lane holds B[k=quad*8+j][col=tile*16+n], j contiguous.
  sh8 z1f[8], w3f[4], g1f[2], g2f;
  #pragma unroll
  for (int t = 0; t < 8; ++t) {
    short tmp[8];
    #pragma unroll
    for (int j = 0; j < 8; ++j) {
      int k = quad * 8 + j, col = t * 16 + n;
      float v = 0.0f;
      if (k < 10) v = dW1[k * HID + col];
      else if (k == 10) v = dW1[106 * HID + col];
      tmp[j] = f2bf(v);
    }
    z1f[t] = (sh8){tmp[0],tmp[1],tmp[2],tmp[3],tmp[4],tmp[5],tmp[6],tmp[7]};
  }
  #pragma unroll
  for (int kt = 0; kt < 4; ++kt) {
    short tmp[8];
    #pragma unroll
    for (int j = 0; j < 8; ++j) {
      int k = kt * 32 + quad * 8 + j;
      tmp[j] = f2bf((n < 10) ? dW3[k * 10 + n] : 0.0f);
    }
    w3f[kt] = (sh8){tmp[0],tmp[1],tmp[2],tmp[3],tmp[4],tmp[5],tmp[6],tmp[7]};
  }
  #pragma unroll
  for (int t = 0; t < 2; ++t) {
    short tmp[8];
    #pragma unroll
    for (int j = 0; j < 8; ++j) {
      int k = quad * 8 + j, col = t * 16 + n;
      float v = 0.0f;
      if (k < 10) v = gW1[k * 32 + col];
      else if (k == 10) v = gW1[10 * 32 + col];
      tmp[j] = f2bf(v);
    }
    g1f[t] = (sh8){tmp[0],tmp[1],tmp[2],tmp[3],tmp[4],tmp[5],tmp[6],tmp[7]};
  }
  {
    short tmp[8];
    #pragma unroll
    for (int j = 0; j < 8; ++j) {
      int k = quad * 8 + j;
      tmp[j] = f2bf((n < 10) ? gW2[k * 10 + n] : 0.0f);
    }
    g2f = (sh8){tmp[0],tmp[1],tmp[2],tmp[3],tmp[4],tmp[5],tmp[6],tmp[7]};
  }
  float db2r[8];
  #pragma unroll
  for (int t = 0; t < 8; ++t) db2r[t] = db2[t * 16 + n];
  float gb1r[2];
  #pragma unroll
  for (int t = 0; t < 2; ++t) gb1r[t] = gb1[t * 16 + n];
  float db3r = (n < 10) ? db3[n] : 0.0f;
  float gb2r = (n < 10) ? gb2[n] : 0.0f;

  __syncthreads();   // ar (union) dead; steady LDS region now writable

  // ---- zero zb, fill ts table ----
  for (int idx = tid; idx < MT * 24; idx += 256) ((short*)lds.u.s.zb)[idx] = 0;
  if (tid < 101) lds.u.s.tsl[tid] = ts[tid];

  // ---- z0 load (fp32 master in VGPRs, D-layout rows), out[0] write ----
  float zreg[4];
  #pragma unroll
  for (int r = 0; r < 4; ++r) {
    int mg = mblk + slab + quad * 4 + r;
    float v = (n < 10) ? z0[mg * 10 + n] : 0.0f;
    zreg[r] = v;
    if (n < 10) out[(size_t)mg * 10 + n] = v;
  }
  __syncthreads();   // zb zeros + tsl visible to all

  float t0 = ts[0];
  #pragma unroll
  for (int r = 0; r < 4; ++r) {
    int ml = slab + quad * 4 + r;
    if (n < 10)       lds.u.s.zb[ml][n]  = f2bf(zreg[r]);
    else if (n == 10) lds.u.s.zb[ml][10] = f2bf(t0);
  }
  // NOTE: zb rows are written by their own wave -> no barrier needed below.

  const sh8 zero8 = {0,0,0,0,0,0,0,0};

  #pragma unroll 1
  for (int s = 0; s < NSTEP; ++s) {
    float tnext = lds.u.s.tsl[s + 1];
    float dtv   = tnext - lds.u.s.tsl[s];
    float sdt   = sqrtf(dtv);

    // z A-frag: lane row m=slab+n, k=quad*8+j; quads 2,3 are zero (K pad)
    sh8 zA = zero8;
    if (quad < 2) zA = *(const sh8*)&lds.u.s.zb[slab + n][quad * 8];

    // ---- drift layer1: h1 = tanh(zt @ Z1ext + c1) ----
    f32x4 a1[8];
    #pragma unroll
    for (int t = 0; t < 8; ++t) {
      f32x4 c = {c1v[t][0], c1v[t][1], c1v[t][2], c1v[t][3]};
      a1[t] = __builtin_amdgcn_mfma_f32_16x16x32_bf16(zA, z1f[t], c, 0, 0, 0);
    }
    #pragma unroll
    for (int t = 0; t < 8; ++t)
      #pragma unroll
      for (int r = 0; r < 4; ++r)
        lds.u.s.h[slab + quad * 4 + r][t * 16 + n] = f2bf(tanh_fast(a1[t][r]));

    // ---- drift layer2: h2 = tanh(h1 @ W2 + db2) ----
    sh8 a2[4];
    #pragma unroll
    for (int kt = 0; kt < 4; ++kt)
      a2[kt] = *(const sh8*)&lds.u.s.h[slab + n][kt * 32 + quad * 8];
    f32x4 acc2[8];
    #pragma unroll
    for (int t = 0; t < 8; ++t) {
      f32x4 c = {db2r[t], db2r[t], db2r[t], db2r[t]};
      #pragma unroll
      for (int kt = 0; kt < 4; ++kt) {
        sh8 b = *(const sh8*)&lds.w2t[t * 16 + n][kt * 32 + quad * 8];
        c = __builtin_amdgcn_mfma_f32_16x16x32_bf16(a2[kt], b, c, 0, 0, 0);
      }
      acc2[t] = c;
    }
    #pragma unroll
    for (int t = 0; t < 8; ++t)
      #pragma unroll
      for (int r = 0; r < 4; ++r)
        lds.u.s.h[slab + quad * 4 + r][t * 16 + n] = f2bf(tanh_fast(acc2[t][r]));

    // ---- drift layer3: drift = h2 @ W3 + db3 (cols 0..9 valid) ----
    sh8 a3[4];
    #pragma unroll
    for (int kt = 0; kt < 4; ++kt)
      a3[kt] = *(const sh8*)&lds.u.s.h[slab + n][kt * 32 + quad * 8];
    f32x4 accd = {db3r, db3r, db3r, db3r};
    #pragma unroll
    for (int kt = 0; kt < 4; ++kt)
      accd = __builtin_amdgcn_mfma_f32_16x16x32_bf16(a3[kt], w3f[kt], accd, 0, 0, 0);

    // ---- diffusion: hg = softplus(zt @ G1ext + gb1); diff = hg @ G2 + gb2 ----
    #pragma unroll
    for (int t = 0; t < 2; ++t) {
      f32x4 c = {gb1r[t], gb1r[t], gb1r[t], gb1r[t]};
      f32x4 g = __builtin_amdgcn_mfma_f32_16x16x32_bf16(zA, g1f[t], c, 0, 0, 0);
      #pragma unroll
      for (int r = 0; r < 4; ++r)
        lds.u.s.hg[slab + quad * 4 + r][t * 16 + n] = f2bf(softplus_fast(g[r]));
    }
    sh8 ag = *(const sh8*)&lds.u.s.hg[slab + n][quad * 8];
    f32x4 accf = {gb2r, gb2r, gb2r, gb2r};
    accf = __builtin_amdgcn_mfma_f32_16x16x32_bf16(ag, g2f, accf, 0, 0, 0);

    // ---- Euler-Maruyama update + output + refresh z-LDS ----
    #pragma unroll
    for (int r = 0; r < 4; ++r) {
      int ml = slab + quad * 4 + r;
      int mg = mblk + ml;
      float eps = 0.0f;
      if (n < 10) eps = noise[((size_t)s * B_TOT + mg) * 10 + n];
      zreg[r] += accd[r] * dtv + accf[r] * sdt * eps;
      if (n < 10) {
        out[((size_t)(s + 1) * B_TOT + mg) * 10 + n] = zreg[r];
        lds.u.s.zb[ml][n] = f2bf(zreg[r]);
      } else if (n == 10) {
        lds.u.s.zb[ml][10] = f2bf(tnext);
      }
    }
  }
}

extern "C" void kernel_launch(void* const* d_in, const int* in_sizes, int n_in,
                              void* d_out, int out_size, void* d_ws, size_t ws_size,
                              hipStream_t stream) {
  (void)in_sizes; (void)n_in; (void)d_ws; (void)ws_size; (void)out_size;
  const float* z0       = (const float*)d_in[0];
  const float* activity = (const float*)d_in[1];
  const float* rest     = (const float*)d_in[2];
  const float* ts       = (const float*)d_in[3];
  const float* noise    = (const float*)d_in[4];
  const float* aW1 = (const float*)d_in[5];
  const float* ab1 = (const float*)d_in[6];
  const float* aW2 = (const float*)d_in[7];
  const float* ab2 = (const float*)d_in[8];
  const float* rW1 = (const float*)d_in[9];
  const float* rb1 = (const float*)d_in[10];
  const float* rW2 = (const float*)d_in[11];
  const float* rb2 = (const float*)d_in[12];
  const float* dW1 = (const float*)d_in[13];
  const float* db1 = (const float*)d_in[14];
  const float* dW2 = (const float*)d_in[15];
  const float* db2 = (const float*)d_in[16];
  const float* dW3 = (const float*)d_in[17];
  const float* db3 = (const float*)d_in[18];
  const float* gW1 = (const float*)d_in[19];
  const float* gb1 = (const float*)d_in[20];
  const float* gW2 = (const float*)d_in[21];
  const float* gb2 = (const float*)d_in[22];
  float* out = (float*)d_out;

  dim3 grid(B_TOT / MT), block(256);
  sde_kernel<<<grid, block, 0, stream>>>(
      z0, activity, rest, ts, noise,
      aW1, ab1, aW2, ab2, rW1, rb1, rW2, rb2,
      dW1, db1, dW2, db2, dW3, db3,
      gW1, gb1, gW2, gb2, out);
}